// Round 2
// baseline (157.648 us; speedup 1.0000x reference)
//
#include <hip/hip_runtime.h>

// Problem constants (B,R,C = 32, NB=2, NC=20)
#define Bdim 32
#define Rdim 32
#define Cdim 32
#define NBOX 2
#define NCLS 20
#define CH   174   // 6 + 2*(R+C) + 2*NC
#define CHP  348   // NB * CH
#define BASE 134   // 6 + 2*(R+C)
#define NCELL (Bdim * Rdim * Cdim)   // 32768

// pred_mask channel-set membership for combo (n, best):
//   {2n+b} ∪ {4+4n+2b,+1} ∪ [12+128n+64b, +64) ∪ [268+40n+20b, +20)
__device__ __forceinline__ bool in_pred(int j, int n, int b) {
    return (j == 2 * n + b)
        || ((unsigned)(j - (4 + 4 * n + 2 * b)) < 2u)
        || ((unsigned)(j - (12 + 128 * n + 64 * b)) < 64u)
        || ((unsigned)(j - (268 + 40 * n + 20 * b)) < 20u);
}

// label_mask channel-set membership for n (best-independent):
//   {n} ∪ {2+2n,+1} ∪ [6+64n, +64) ∪ [134+20n, +20)
__device__ __forceinline__ bool in_lab(int j, int n) {
    return (j == n)
        || ((unsigned)(j - (2 + 2 * n)) < 2u)
        || ((unsigned)(j - (6 + 64 * n)) < 64u)
        || ((unsigned)(j - (134 + 20 * n)) < 20u);
}

// Pass 1: one wave per cell. Wave-uniform flag check; ballot argmax of the
// exact one-hots; redundant per-lane score math (all loads broadcast).
// Writes flagbest[cell] = 0 | (1+best); atomicOr corner bits at corner cell.
__global__ __launch_bounds__(256) void match_kernel(
    const float* __restrict__ pred, const float* __restrict__ label,
    int* __restrict__ flagbest, int* __restrict__ corner)
{
    const int cell = (blockIdx.x << 2) | (threadIdx.x >> 6);
    const int lane = threadIdx.x & 63;
    const int c = cell & 31;
    const int r = (cell >> 5) & 31;
    const int b = cell >> 10;

    const float* Lcell = label + (size_t)cell * CH;

    if (Lcell[0] != 1.0f) {             // wave-uniform
        if (lane == 0) flagbest[cell] = 0;
        return;
    }

    // argmax of one-hot via ballot (first set bit == first max index)
    float vr = (lane < 32) ? Lcell[6 + lane] : 0.0f;
    float vc = (lane < 32) ? Lcell[6 + 32 + lane] : 0.0f;
    unsigned long long mr = __ballot(lane < 32 && vr == 1.0f);
    unsigned long long mc = __ballot(lane < 32 && vc == 1.0f);
    const int rowc = mr ? (int)__builtin_ctzll(mr) : 0;
    const int colc = mc ? (int)__builtin_ctzll(mc) : 0;

    const int cornIdx = (b * Rdim + rowc) * Cdim + colc;
    const float* Lcorn = label + (size_t)cornIdx * CH;
    const float* Pcell = pred + (size_t)cell * CHP;
    const float* Pcorn = pred + (size_t)cornIdx * CHP;

    const float inv = 0.03125f;   // 1/32 exact
    float xm_t = (Lcell[2] + (float)c) * inv;
    float ym_t = (Lcell[3] + (float)r) * inv;
    float xc_t = (Lcorn[4] + (float)colc) * inv;
    float yc_t = (Lcorn[5] + (float)rowc) * inv;
    float tw = fabsf(xm_t - xc_t) * 2.0f;
    float th = fabsf(ym_t - yc_t) * 2.0f;

    float score[NBOX];
#pragma unroll
    for (int i = 0; i < NBOX; ++i) {
        float cat = 0.0f;
#pragma unroll
        for (int k = 0; k < NCLS; ++k) {
            float d1 = Pcell[268 + i * NCLS + k] - Lcell[BASE + k];
            float d2 = Pcorn[308 + i * NCLS + k] - Lcorn[BASE + NCLS + k];
            cat += d1 * d1 + d2 * d2;
        }
        float conn_m = Pcell[12 + i * 64 + rowc] * Pcell[12 + i * 64 + 32 + colc];
        float conn_c = Pcorn[140 + i * 64 + r]   * Pcorn[140 + i * 64 + 32 + c];
        float conn = (conn_m + conn_c) * 0.5f;
        float xm_p = Pcell[(NBOX + i) * 2 + 0 + c] * inv;
        float ym_p = Pcell[(NBOX + i) * 2 + 1 + r] * inv;
        float xc_p = Pcorn[(NBOX * 2 + i) * 2 + 0 + colc] * inv;
        float yc_p = Pcorn[(NBOX * 2 + i) * 2 + 1 + rowc] * inv;
        float ow = fabsf(xm_p - xc_p) * 2.0f;
        float oh = fabsf(ym_p - yc_p) * 2.0f;
        float w = fminf(xm_p + ow * 0.5f, xm_t + tw * 0.5f)
                - fmaxf(xm_p - ow * 0.5f, xm_t - tw * 0.5f);
        float h = fminf(ym_p + oh * 0.5f, ym_t + th * 0.5f)
                - fmaxf(ym_p - oh * 0.5f, ym_t - th * 0.5f);
        float inter = (w < 0.0f || h < 0.0f) ? 0.0f : w * h;
        float uni = ow * oh + tw * th - inter;
        float iou = inter / uni;
        float rmse = (xm_p - xm_t) * (xm_p - xm_t) + (ym_p - ym_t) * (ym_p - ym_t)
                   + (ow - tw) * (ow - tw) + (oh - th) * (oh - th);
        score[i] = conn * (iou - rmse + 0.1f) + 0.1f * (2.0f - cat);
    }
    const int best = (score[1] > score[0]) ? 1 : 0;

    if (lane == 0) {
        flagbest[cell] = 1 + best;
        atomicOr(&corner[cornIdx], 1 << best);   // device-scope, ~5K total
    }
}

// Pass 2: one wave per cell writes the cell's full 696-float output exactly
// once (no memset of d_out, no RMW). Coalesced float4 (pred_mask row,
// 16B-aligned: 348*4=1392=16*87) and float2 (label rows, 696B base -> 8B
// aligned) stores; 87 iterations split lane/lane+64.
__global__ __launch_bounds__(256) void write_kernel(
    const int* __restrict__ flagbest, const int* __restrict__ corner,
    float* __restrict__ out0, float* __restrict__ out1, float* __restrict__ out2)
{
    const int cell = (blockIdx.x << 2) | (threadIdx.x >> 6);
    const int lane = threadIdx.x & 63;

    const int fb = flagbest[cell];   // broadcast load
    const int cb = corner[cell];

    float4* __restrict__ o0 = (float4*)(out0 + (size_t)cell * CHP);
    float2* __restrict__ o1 = (float2*)(out1 + (size_t)cell * CH);
    float2* __restrict__ o2 = (float2*)(out2 + (size_t)cell * CH);

    if ((fb | cb) == 0) {            // wave-uniform fast path: all-zero row
        const float4 z4 = make_float4(0.f, 0.f, 0.f, 0.f);
        const float2 z2 = make_float2(0.f, 0.f);
        for (int t = lane; t < 87; t += 64) { o0[t] = z4; o1[t] = z2; o2[t] = z2; }
        return;
    }

    const bool flag = fb > 0;
    const int  b0   = flag ? fb - 1 : 0;
    const bool c0   = (cb & 1) != 0;
    const bool c1   = (cb & 2) != 0;
    const bool anyc = c0 | c1;

    for (int t = lane; t < 87; t += 64) {
        // pred_mask: channels [4t, 4t+4)
        float4 v;
        float* vp = (float*)&v;
#pragma unroll
        for (int e = 0; e < 4; ++e) {
            const int j = 4 * t + e;
            const bool x = (flag && in_pred(j, 0, b0))
                        || (c0   && in_pred(j, 1, 0))
                        || (c1   && in_pred(j, 1, 1));
            vp[e] = x ? 1.0f : 0.0f;
        }
        o0[t] = v;

        // label_mask: channels [2t, 2t+2)
        const int k = 2 * t;
        float2 u;
        u.x = ((flag && in_lab(k,     0)) || (anyc && in_lab(k,     1))) ? 1.0f : 0.0f;
        u.y = ((flag && in_lab(k + 1, 0)) || (anyc && in_lab(k + 1, 1))) ? 1.0f : 0.0f;
        o1[t] = u;
        o2[t] = u;
    }
}

extern "C" void kernel_launch(void* const* d_in, const int* in_sizes, int n_in,
                              void* d_out, int out_size, void* d_ws, size_t ws_size,
                              hipStream_t stream) {
    const float* pred  = (const float*)d_in[0];
    const float* label = (const float*)d_in[1];
    // d_in[2]/d_in[3] = num_box/num_class, hard-coded as NBOX/NCLS

    float* out0 = (float*)d_out;                                   // pred_mask
    float* out1 = out0 + (size_t)NCELL * CHP;                      // label_mask
    float* out2 = out1 + (size_t)NCELL * CH;                       // label_mask copy

    int* flagbest = (int*)d_ws;                                    // [NCELL]
    int* corner   = flagbest + NCELL;                              // [NCELL]

    // only the corner-scatter array needs zeroing (128 KB, ws is 0xAA-poisoned)
    hipMemsetAsync(corner, 0, NCELL * sizeof(int), stream);

    const int blocks = NCELL / 4;   // 4 waves (4 cells) per 256-thread block
    match_kernel<<<blocks, 256, 0, stream>>>(pred, label, flagbest, corner);
    write_kernel<<<blocks, 256, 0, stream>>>(flagbest, corner, out0, out1, out2);
}